// Round 8
// baseline (792.165 us; speedup 1.0000x reference)
//
#include <hip/hip_runtime.h>
#include <hip/hip_bf16.h>
#include <math.h>

// Problem constants
#define B_    8
#define N1_   4096
#define N2_   4096
#define C_    512
#define P_    256
#define H_    8
#define MLP_  2048
#define HD_   64

typedef __hip_bfloat16 bf16;
typedef __attribute__((ext_vector_type(8))) short short8;   // 8 bf16 (4 VGPRs)
typedef __attribute__((ext_vector_type(4))) float f32x4;

__device__ __forceinline__ float bf2f(bf16 v) { return __bfloat162float(v); }
__device__ __forceinline__ bf16  f2bf(float v) { return __float2bfloat16(v); }
__device__ __forceinline__ float ubf2f(unsigned short u) {
  union { float f; unsigned int i; } cv; cv.i = ((unsigned int)u) << 16; return cv.f;
}
__device__ __forceinline__ unsigned short f2bfu(float v) {
  union { bf16 b; unsigned short u; } cv; cv.b = __float2bfloat16(v); return cv.u;
}
// exact-erf gelu. NOTE: r6 A/B showed the "fast" branchless erf REGRESSES
// (VGPR 76->88, occupancy 30->21%) — keep ocml erff.
__device__ __forceinline__ float gelu_exact(float x) {
  return 0.5f * x * (1.0f + erff(x * 0.70710678118654752f));
}

// async global->LDS, 16B per lane (global_load_lds_dwordx4)
__device__ __forceinline__ void gload16(const void* g, void* l) {
  __builtin_amdgcn_global_load_lds(
      (const __attribute__((address_space(1))) void*)g,
      (__attribute__((address_space(3))) void*)l, 16, 0, 0);
}

// ---------------------------------------------------------------------------
// f32 -> bf16 elementwise (x1/x2 conversion). n4 = count/4.
__global__ __launch_bounds__(256) void f2b_kernel(
    const float* __restrict__ in, bf16* __restrict__ out, int n4)
{
  int i = blockIdx.x * 256 + threadIdx.x;
  const int stride = gridDim.x * 256;
  for (; i < n4; i += stride) {
    const float4 v = ((const float4*)in)[i];
    ushort4 o;
    o.x = f2bfu(v.x); o.y = f2bfu(v.y); o.z = f2bfu(v.z); o.w = f2bfu(v.w);
    ((ushort4*)out)[i] = o;
  }
}

// f32 (K,N) row-major (leading dim ldin) -> bf16 (N,K) transposed.
__global__ __launch_bounds__(256) void transpose_f2b_kernel(
    const float* __restrict__ in, bf16* __restrict__ out, int K, int N, int ldin)
{
  __shared__ float tile[32][33];
  const int kb = blockIdx.y * 32, nb = blockIdx.x * 32;
  const int tx = threadIdx.x & 31, ty = threadIdx.x >> 5;  // ty = 0..7
  #pragma unroll
  for (int i = 0; i < 4; ++i)
    tile[ty + 8 * i][tx] = in[(size_t)(kb + ty + 8 * i) * ldin + nb + tx];
  __syncthreads();
  #pragma unroll
  for (int i = 0; i < 4; ++i)
    out[(size_t)(nb + ty + 8 * i) * K + kb + tx] = f2bf(tile[tx][ty + 8 * i]);
}

// ---------------------------------------------------------------------------
// MFMA bf16 GEMM (m97 structure, SINGLE-buffered — r7 dbuf A/B was null/neg).
// C = A @ Bt^T (+bias +pos, opt gelu). A: (M,K) bf16. Bt: (N,K) bf16.
// XCD swizzle: each XCD owns contiguous row-major tiles (A-panel L2 reuse).
// TRANSC=1 (fused kv only): output TRANSPOSED [b][c][n2]; n<512 -> Cv (kT,
// +pos), n>=512 -> Cv2 (vT). Per-lane 4 consecutive m -> ushort4 store.
template<int BN, int OUTF32, int ACT, int POS, int TRANSC>
__global__ __launch_bounds__(256) void mfma_gemm_kernel(
    const bf16* __restrict__ A, const bf16* __restrict__ Bt,
    const float* __restrict__ bias, const float* __restrict__ pos, int posmask,
    void* __restrict__ Cv, void* __restrict__ Cv2, int M, int N, int K)
{
  constexpr int WGN = BN / 64;            // wave-grid cols (2 or 1)
  constexpr int WGR = 4 / WGN;            // wave-grid rows (2 or 4)
  constexpr int FM  = 128 / (16 * WGR);   // A fragments per wave (4 or 2)
  __shared__ bf16 As[128 * 32];           // [m][k], row = 64B
  __shared__ bf16 Bs[BN * 32];            // [n][k]
  const int t  = threadIdx.x;
  const int l  = t & 63;
  const int w  = t >> 6;
  const int wr = w / WGN, wc = w % WGN;
  const int lr = l & 15, kg = l >> 4;

  // ---- XCD-aware tile remap ----
  const int gx  = gridDim.x;
  const int nwg = gx * gridDim.y;
  const int h   = blockIdx.y * gx + blockIdx.x;
  int bx = blockIdx.x, by = blockIdx.y;
  if ((nwg & 7) == 0) {
    const int tid = (h & 7) * (nwg >> 3) + (h >> 3);
    bx = tid % gx; by = tid / gx;
  }
  const int m0 = by * 128, n0 = bx * BN;

  const bf16* ga = A  + (size_t)(m0 + (t >> 2)) * K + (t & 3) * 8;
  const bf16* gb = Bt + (size_t)(n0 + (t >> 2)) * K + (t & 3) * 8;
  char* asl = (char*)As + t * 16;
  char* bsl = (char*)Bs + t * 16;

  f32x4 acc[FM][4] = {};

  for (int k0 = 0; k0 < K; k0 += 32) {
    gload16(ga, asl);
    gload16(ga + (size_t)64 * K, asl + 4096);
    gload16(gb, bsl);
    if (BN == 128) gload16(gb + (size_t)64 * K, bsl + 4096);
    ga += 32; gb += 32;
    __syncthreads();
    short8 af[FM], bfv[4];
    #pragma unroll
    for (int i = 0; i < FM; ++i)
      af[i] = *(const short8*)&As[(wr * (FM * 16) + i * 16 + lr) * 32 + kg * 8];
    #pragma unroll
    for (int j = 0; j < 4; ++j)
      bfv[j] = *(const short8*)&Bs[(wc * 64 + j * 16 + lr) * 32 + kg * 8];
    #pragma unroll
    for (int i = 0; i < FM; ++i)
      #pragma unroll
      for (int j = 0; j < 4; ++j)
        acc[i][j] = __builtin_amdgcn_mfma_f32_16x16x32_bf16(
            af[i], bfv[j], acc[i][j], 0, 0, 0);
    __syncthreads();
  }

  #pragma unroll
  for (int i = 0; i < FM; ++i) {
    #pragma unroll
    for (int j = 0; j < 4; ++j) {
      const int n = n0 + wc * 64 + j * 16 + lr;
      const float bv = bias[n];
      if (TRANSC) {
        const int mb = m0 + wr * (FM * 16) + i * 16 + kg * 4;   // 4-aligned
        ushort4 pk;
        #pragma unroll
        for (int r = 0; r < 4; ++r) {
          float v = acc[i][j][r] + bv;
          if (POS && n < C_) v += pos[(size_t)((mb + r) & posmask) * C_ + n];
          ((unsigned short*)&pk)[r] = f2bfu(v);
        }
        bf16* ob = (bf16*)(n < C_ ? Cv : Cv2);
        const int nc = n & (C_ - 1);
        *(ushort4*)&ob[((size_t)(mb >> 12) * C_ + nc) * (size_t)N1_ + (mb & 4095)] = pk;
      } else {
        #pragma unroll
        for (int r = 0; r < 4; ++r) {
          const int m = m0 + wr * (FM * 16) + i * 16 + kg * 4 + r;
          float v = acc[i][j][r] + bv;
          if (POS) v += pos[(size_t)(m & posmask) * N + n];
          if (ACT) v = gelu_exact(v);
          if (OUTF32) ((float*)Cv)[(size_t)m * N + n] = v;
          else        ((bf16*)Cv)[(size_t)m * N + n] = f2bf(v);
        }
      }
    }
  }
}

// ---------------------------------------------------------------------------
// Fused kp/vp projection, both sides in ONE launch (z<64: kpT, else vp).
// kpT[z][p][d] = (WpT @ kT[z]^T)[p][d] + bp[p]        (M=256, N=64)
// vp[z'][d][p] = (vT[z'] @ WpT^T)[d][p] + bp[p]       (M=64,  N=256)
// Single-buffered m97 loop, K=4096. Block-uniform side select (no divergence).
__global__ __launch_bounds__(256) void proj_both_kernel(
    const bf16* __restrict__ WpT, const bf16* __restrict__ kT,
    const bf16* __restrict__ vT, const float* __restrict__ bp,
    bf16* __restrict__ kpT, bf16* __restrict__ vpb)
{
  __shared__ bf16 As[64 * 32];
  __shared__ bf16 Bs[64 * 32];
  const int t = threadIdx.x, l = t & 63, w = t >> 6;
  const int wr = w >> 1, wc = w & 1;
  const int lr = l & 15, kg = l >> 4;
  const int zz = blockIdx.z;
  const int isk = (zz < 64) ? 1 : 0;
  const int z  = isk ? zz : zz - 64;
  const int K  = N2_;
  const int m0 = isk ? blockIdx.x * 64 : 0;
  const int n0 = isk ? 0 : blockIdx.x * 64;
  const int N  = isk ? HD_ : P_;
  const bf16* Ab  = isk ? WpT : (vT + (size_t)z * HD_ * N2_);
  const bf16* Btb = isk ? (kT + (size_t)z * HD_ * N2_) : WpT;
  bf16* Cb = isk ? (kpT + (size_t)z * P_ * HD_) : (vpb + (size_t)z * HD_ * P_);

  const bf16* ga = Ab  + (size_t)(m0 + (t >> 2)) * K + (t & 3) * 8;
  const bf16* gb = Btb + (size_t)(n0 + (t >> 2)) * K + (t & 3) * 8;
  char* asl = (char*)As + t * 16;
  char* bsl = (char*)Bs + t * 16;
  f32x4 acc[2][2] = {};
  for (int k0 = 0; k0 < K; k0 += 32) {
    gload16(ga, asl);
    gload16(gb, bsl);
    ga += 32; gb += 32;
    __syncthreads();
    short8 af[2], bfr[2];
    #pragma unroll
    for (int i = 0; i < 2; ++i)
      af[i] = *(const short8*)&As[(wr * 32 + i * 16 + lr) * 32 + kg * 8];
    #pragma unroll
    for (int j = 0; j < 2; ++j)
      bfr[j] = *(const short8*)&Bs[(wc * 32 + j * 16 + lr) * 32 + kg * 8];
    #pragma unroll
    for (int i = 0; i < 2; ++i)
      #pragma unroll
      for (int j = 0; j < 2; ++j)
        acc[i][j] = __builtin_amdgcn_mfma_f32_16x16x32_bf16(
            af[i], bfr[j], acc[i][j], 0, 0, 0);
    __syncthreads();
  }
  #pragma unroll
  for (int i = 0; i < 2; ++i)
    #pragma unroll
    for (int j = 0; j < 2; ++j) {
      const int n = n0 + wc * 32 + j * 16 + lr;
      #pragma unroll
      for (int r = 0; r < 4; ++r) {
        const int m = m0 + wr * 32 + i * 16 + kg * 4 + r;
        const float v = acc[i][j][r] + (isk ? bp[m] : bp[n]);
        Cb[(size_t)m * N + n] = f2bf(v);
      }
    }
}

// ---------------------------------------------------------------------------
// MFMA attention. One block = (b,h) x 64 q-rows, 4 waves. Output transposed:
// xatT[b,h,d,q] (norm1's scramble gather becomes contiguous).
__global__ __launch_bounds__(256) void attn_mfma_kernel(
    const bf16* __restrict__ qb, const bf16* __restrict__ kpT,
    const bf16* __restrict__ vp, const float* __restrict__ temp,
    bf16* __restrict__ xatT)
{
  __shared__ bf16 qs[64 * 64];
  __shared__ bf16 us[256 * 64];
  __shared__ bf16 vs[64 * 256];
  const int t = threadIdx.x, w = t >> 6, l = t & 63;
  const int lr = l & 15, kg = l >> 4;
  const int b = blockIdx.z, h = blockIdx.y;
  const int q0 = blockIdx.x * 64;
  const int bh = b * H_ + h;
  const float tv = temp[h];

  // ---- stage q / kpT / vp (reg-staged, swizzled 16B writes) ----
  {
    const int rowb = t >> 3, ch = t & 7;        // 128B rows
    #pragma unroll
    for (int p = 0; p < 2; ++p) {
      const int r = rowb + 32 * p;
      const short8 v = *(const short8*)(qb + ((size_t)(b * N1_ + q0 + r)) * C_ + h * HD_ + ch * 8);
      *(short8*)((char*)qs + ((r * 128 + ch * 16) ^ ((r & 7) << 4))) = v;
    }
    const bf16* kpb = kpT + (size_t)bh * (P_ * HD_);
    #pragma unroll
    for (int p = 0; p < 8; ++p) {
      const int r = rowb + 32 * p;
      const short8 v = *(const short8*)(kpb + r * HD_ + ch * 8);
      *(short8*)((char*)us + ((r * 128 + ch * 16) ^ ((r & 7) << 4))) = v;
    }
    const bf16* vpb = vp + (size_t)bh * (HD_ * P_);
    const int rowv = t >> 5, chv = t & 31;      // 512B rows
    #pragma unroll
    for (int p = 0; p < 8; ++p) {
      const int r = rowv + 8 * p;
      const short8 v = *(const short8*)(vpb + r * P_ + chv * 8);
      *(short8*)((char*)vs + ((r * 512 + chv * 16) ^ ((r & 7) << 4))) = v;
    }
  }
  __syncthreads();

  // ---- S-phase: s[j] = q(16 rows) x kpT-tile j (16 p), K=64 ----
  short8 aq[2];
  {
    const int row = w * 16 + lr;
    const int sw = (row & 7) << 4;
    aq[0] = *(const short8*)((const char*)qs + ((row * 128 +  0 + kg * 16) ^ sw));
    aq[1] = *(const short8*)((const char*)qs + ((row * 128 + 64 + kg * 16) ^ sw));
  }
  f32x4 s[16] = {};
  #pragma unroll
  for (int j = 0; j < 16; ++j) {
    const int row = j * 16 + lr;
    const int sw = (row & 7) << 4;
    const short8 b0 = *(const short8*)((const char*)us + ((row * 128 +  0 + kg * 16) ^ sw));
    const short8 b1 = *(const short8*)((const char*)us + ((row * 128 + 64 + kg * 16) ^ sw));
    s[j] = __builtin_amdgcn_mfma_f32_16x16x32_bf16(aq[0], b0, s[j], 0, 0, 0);
    s[j] = __builtin_amdgcn_mfma_f32_16x16x32_bf16(aq[1], b1, s[j], 0, 0, 0);
  }

  // ---- softmax over p (256) per q-row; row q = w*16 + kg*4 + r ----
  float inv_[4];
  #pragma unroll
  for (int j = 0; j < 16; ++j)
    #pragma unroll
    for (int r = 0; r < 4; ++r) s[j][r] *= tv;
  #pragma unroll
  for (int r = 0; r < 4; ++r) {
    float m = s[0][r];
    #pragma unroll
    for (int j = 1; j < 16; ++j) m = fmaxf(m, s[j][r]);
    #pragma unroll
    for (int off = 1; off < 16; off <<= 1) m = fmaxf(m, __shfl_xor(m, off));
    float sum = 0.f;
    #pragma unroll
    for (int j = 0; j < 16; ++j) { s[j][r] = __expf(s[j][r] - m); sum += s[j][r]; }
    #pragma unroll
    for (int off = 1; off < 16; off <<= 1) sum += __shfl_xor(sum, off);
    inv_[r] = 1.0f / sum;
  }
  __syncthreads();   // all waves done reading kpT from us

  // ---- write P (bf16) into us as [q 64][p 256], swizzled ----
  #pragma unroll
  for (int r = 0; r < 4; ++r) {
    const int q = w * 16 + kg * 4 + r;
    const int sw = (q & 7) << 4;
    #pragma unroll
    for (int j = 0; j < 16; ++j) {
      const int p = j * 16 + lr;
      ((unsigned short*)us)[((q * 512 + p * 2) ^ sw) >> 1] = f2bfu(s[j][r] * inv_[r]);
    }
  }
  __syncthreads();

  // ---- PV-phase: O^T = vp @ P^T  (A = vp d-rows, B = P q-rows) ----
  f32x4 o[4] = {};
  #pragma unroll
  for (int kc = 0; kc < 8; ++kc) {
    const int qrow = w * 16 + lr;
    const short8 pb = *(const short8*)((const char*)us +
        ((qrow * 512 + kc * 64 + kg * 16) ^ ((qrow & 7) << 4)));
    #pragma unroll
    for (int i = 0; i < 4; ++i) {
      const int drow = i * 16 + lr;
      const short8 vb = *(const short8*)((const char*)vs +
          ((drow * 512 + kc * 64 + kg * 16) ^ ((drow & 7) << 4)));
      o[i] = __builtin_amdgcn_mfma_f32_16x16x32_bf16(vb, pb, o[i], 0, 0, 0);
    }
  }
  // D[m=d][n=q]: q = w*16 + lr, d = i*16 + kg*4 + r.
  const int qq = q0 + w * 16 + lr;
  bf16* ob = xatT + (size_t)bh * (HD_ * (size_t)N1_) + qq;
  #pragma unroll
  for (int i = 0; i < 4; ++i)
    #pragma unroll
    for (int r = 0; r < 4; ++r) {
      const int d = i * 16 + kg * 4 + r;
      ob[(size_t)d * N1_] = f2bf(o[i][r]);
    }
}

// ---------------------------------------------------------------------------
// x = l2norm(scramble(attn) + q_skip). With xatT[b,h,d,q] the gather for
// output row n=(d,h,qhi) column c is CONTIGUOUS: xatT[bh][d][qhi*512 + c].
__global__ __launch_bounds__(256) void norm1_kernel(
    const bf16* __restrict__ xatT, const bf16* __restrict__ qb,
    bf16* __restrict__ xb)
{
  const int row = blockIdx.x;                  // b*4096 + n
  const int b = row >> 12, np = row & 4095;
  const int d = np >> 6, h = (np >> 3) & 7, qhi = np & 7;
  const int c = threadIdx.x * 2;
  const size_t tbase = ((size_t)(b * H_ + h) * HD_ + d) * N1_ + qhi * 512 + c;
  const size_t qbase = (size_t)row * C_ + c;
  const ushort2 xa = *(const ushort2*)((const unsigned short*)xatT + tbase);
  const ushort2 qa = *(const ushort2*)((const unsigned short*)qb + qbase);
  float v0 = ubf2f(xa.x) + ubf2f(qa.x);
  float v1 = ubf2f(xa.y) + ubf2f(qa.y);
  float ss = v0 * v0 + v1 * v1;
  #pragma unroll
  for (int off = 32; off > 0; off >>= 1) ss += __shfl_xor(ss, off);
  __shared__ float sw[4];
  if ((threadIdx.x & 63) == 0) sw[threadIdx.x >> 6] = ss;
  __syncthreads();
  const float tot = sw[0] + sw[1] + sw[2] + sw[3];
  const float scale = 1.0f / fmaxf(sqrtf(tot), 1e-12f);
  ushort2 o;
  o.x = f2bfu(v0 * scale);
  o.y = f2bfu(v1 * scale);
  *(ushort2*)((unsigned short*)xb + qbase) = o;
}

// ---------------------------------------------------------------------------
// Fused MLP2 + norm2: out = l2norm(h @ W2t^T + b2 + x), f32 out.
// Tile 64 rows x 512 cols (FULL output row -> l2norm in-kernel, yb dead).
// 4 waves 2x2: wave = 32 rows x 256 cols (2 m-frags x 16 n-frags).
// Row sum-of-squares: in-lane over 16 j-frags, shfl over the 16-lane lr
// group, cross-wc via tiny LDS. K=2048, BK=32, single-buffered m97 loop.
__global__ __launch_bounds__(256) void mlp2norm_kernel(
    const bf16* __restrict__ A,      // h  (Mc x 2048) bf16
    const bf16* __restrict__ Bt,     // W2t (512 x 2048) bf16
    const float* __restrict__ bias,  // b2
    const bf16* __restrict__ xr,     // residual x (Mc x 512) bf16
    float* __restrict__ outp)
{
  __shared__ bf16 As[64 * 32];       // 4KB
  __shared__ bf16 Bs[512 * 32];      // 32KB
  __shared__ float rsum[64][2];
  const int t = threadIdx.x, l = t & 63, w = t >> 6;
  const int wr = w >> 1, wc = w & 1;
  const int lr = l & 15, kg = l >> 4;
  const int K = MLP_;

  int by = blockIdx.x;
  const int nwg = gridDim.x;
  if ((nwg & 7) == 0) by = (by & 7) * (nwg >> 3) + (by >> 3);
  const int m0 = by * 64;

  const bf16* ga = A  + (size_t)(m0 + (t >> 2)) * K + (t & 3) * 8;
  const bf16* gb = Bt + (size_t)(t >> 2) * K + (t & 3) * 8;
  char* asl = (char*)As + t * 16;
  char* bsl = (char*)Bs + t * 16;

  f32x4 acc[2][16] = {};

  for (int k0 = 0; k0 < K; k0 += 32) {
    gload16(ga, asl);
    #pragma unroll
    for (int p = 0; p < 8; ++p)
      gload16(gb + (size_t)(p * 64) * K, bsl + p * 4096);
    ga += 32; gb += 32;
    __syncthreads();
    short8 af[2];
    #pragma unroll
    for (int i = 0; i < 2; ++i)
      af[i] = *(const short8*)&As[(wr * 32 + i * 16 + lr) * 32 + kg * 8];
    #pragma unroll
    for (int j = 0; j < 16; ++j) {
      const short8 bv = *(const short8*)&Bs[(wc * 256 + j * 16 + lr) * 32 + kg * 8];
      acc[0][j] = __builtin_amdgcn_mfma_f32_16x16x32_bf16(af[0], bv, acc[0][j], 0, 0, 0);
      acc[1][j] = __builtin_amdgcn_mfma_f32_16x16x32_bf16(af[1], bv, acc[1][j], 0, 0, 0);
    }
    __syncthreads();
  }

  // v = acc + b2[n] + x[m][n]; accumulate per-row sum of squares
  float psum[2][4] = {};
  #pragma unroll
  for (int i = 0; i < 2; ++i)
    #pragma unroll
    for (int j = 0; j < 16; ++j) {
      const int n = wc * 256 + j * 16 + lr;
      const float bv = bias[n];
      #pragma unroll
      for (int r = 0; r < 4; ++r) {
        const int m = m0 + wr * 32 + i * 16 + kg * 4 + r;
        const float v = acc[i][j][r] + bv + bf2f(xr[(size_t)m * C_ + n]);
        acc[i][j][r] = v;
        psum[i][r] = __builtin_fmaf(v, v, psum[i][r]);
      }
    }
  // reduce over the 16-lane lr group (lanes l = kg*16 + lr)
  #pragma unroll
  for (int i = 0; i < 2; ++i)
    #pragma unroll
    for (int r = 0; r < 4; ++r) {
      float s = psum[i][r];
      #pragma unroll
      for (int off = 1; off < 16; off <<= 1) s += __shfl_xor(s, off);
      psum[i][r] = s;
    }
  if (lr == 0) {
    #pragma unroll
    for (int i = 0; i < 2; ++i)
      #pragma unroll
      for (int r = 0; r < 4; ++r)
        rsum[wr * 32 + i * 16 + kg * 4 + r][wc] = psum[i][r];
  }
  __syncthreads();
  float scl[2][4];
  #pragma unroll
  for (int i = 0; i < 2; ++i)
    #pragma unroll
    for (int r = 0; r < 4; ++r) {
      const int row = wr * 32 + i * 16 + kg * 4 + r;
      const float tot = rsum[row][0] + rsum[row][1];
      scl[i][r] = 1.0f / fmaxf(sqrtf(tot), 1e-12f);
    }
  #pragma unroll
  for (int i = 0; i < 2; ++i)
    #pragma unroll
    for (int j = 0; j < 16; ++j) {
      const int n = wc * 256 + j * 16 + lr;
      #pragma unroll
      for (int r = 0; r < 4; ++r) {
        const int m = m0 + wr * 32 + i * 16 + kg * 4 + r;
        outp[(size_t)m * C_ + n] = acc[i][j][r] * scl[i][r];
      }
    }
}

// ---------------------------------------------------------------------------
extern "C" void kernel_launch(void* const* d_in, const int* in_sizes, int n_in,
                              void* d_out, int out_size, void* d_ws, size_t ws_size,
                              hipStream_t stream)
{
  const float* x1   = (const float*)d_in[0];
  const float* x2   = (const float*)d_in[1];
  const float* Wq   = (const float*)d_in[2];
  const float* bq   = (const float*)d_in[3];
  const float* Wkv  = (const float*)d_in[4];
  const float* bkv  = (const float*)d_in[5];
  const float* Wp   = (const float*)d_in[6];
  const float* bp   = (const float*)d_in[7];
  const float* posq = (const float*)d_in[8];
  const float* posk = (const float*)d_in[9];
  const float* temp = (const float*)d_in[10];
  const float* W1   = (const float*)d_in[11];
  const float* b1   = (const float*)d_in[12];
  const float* W2   = (const float*)d_in[13];
  const float* b2   = (const float*)d_in[14];

  // Workspace layout (pre-MLP):
  //  A [0,32M):      x2b -> x1b -> xb
  //  B [32,64M):     vT -> xatT -> hb(start)
  //  C [64,96M):     kT -> qb
  //  [96,98M):       kpT   (dead after attn)
  //  [98,100M):      vp    (dead after attn)
  //  [100,102M):     WpT   (dead after proj)
  //  [102M..):       Wqt/Wkvt
  // MLP phase: hb from 32M (CH*2048*2 B), W1t/W2t per branch. No yb (fused).
  char* ws = (char*)d_ws;
  bf16*  Abuf = (bf16*)(ws);
  bf16*  Bbuf = (bf16*)(ws + 33554432);
  bf16*  Cbuf = (bf16*)(ws + 67108864);
  bf16*  kpT  = (bf16*)(ws + 100663296);
  bf16*  vpb  = (bf16*)(ws + 102760448);
  bf16*  WpT  = (bf16*)(ws + 104857600);
  bf16*  Wqt  = (bf16*)(ws + 106954752);
  bf16*  Wkvt = (bf16*)(ws + 107479040);   // 1 MiB (1024 x 512 bf16)
  float* outp = (float*)d_out;

  // MLP chunk size (no yb needed anymore — norm2 fused into MLP2).
  // need(CH=32768): hb ends at 32M+134M = 160M; W1t/W2t 2M each after.
  int CH;
  size_t w1t_off, w2t_off;
  if (ws_size >= 171966464UL) {            // 164 MiB: single pass
    CH = 32768; w1t_off = 167772160UL; w2t_off = 169869312UL;
  } else {                                 // 4-chunk fallback
    CH = 8192;  w1t_off = 100663296UL; w2t_off = 102760448UL;
  }
  bf16*  W1t = (bf16*)(ws + w1t_off);
  bf16*  W2t = (bf16*)(ws + w2t_off);

  const dim3 blk(256);
  const int Mrows = B_ * N1_;       // 32768
  bf16* xatT = Bbuf;
  bf16* xb   = Abuf;
  bf16* hb   = Bbuf;
  bf16* qb   = Cbuf;
  bf16* kT   = Cbuf;
  bf16* vT   = Bbuf;

  // x2 -> bf16
  f2b_kernel<<<dim3(2048), blk, 0, stream>>>(x2, Abuf, (B_ * N2_ * C_) / 4);
  // weight transposes: f32 (K,N) -> bf16 (N,K)
  transpose_f2b_kernel<<<dim3(32, 16), blk, 0, stream>>>(Wkv, Wkvt, C_, 2 * C_, 2 * C_);
  transpose_f2b_kernel<<<dim3(16, 16), blk, 0, stream>>>(Wq,  Wqt,  C_, C_,     C_);
  transpose_f2b_kernel<<<dim3(8, 128), blk, 0, stream>>>(Wp,  WpT,  N2_, P_,    P_);

  // fused kv: [kT | vT] = (x2 @ Wkv + bkv (+pos_k on k-half))^T, split outputs
  mfma_gemm_kernel<128,0,0,1,1><<<dim3((2*C_)/128, Mrows/128), blk, 0, stream>>>(
      Abuf, Wkvt, bkv, posk, N2_ - 1, kT, vT, Mrows, 2 * C_, C_);
  // kpT + vp in one launch
  proj_both_kernel<<<dim3(4, 1, 2 * B_ * H_), blk, 0, stream>>>(
      WpT, kT, vT, bp, kpT, vpb);
  // x1 -> bf16 (x2b dead)
  f2b_kernel<<<dim3(2048), blk, 0, stream>>>(x1, Abuf, (B_ * N1_ * C_) / 4);
  // q = x1@Wq + bq + pos_q  -> C (kT dead)
  mfma_gemm_kernel<128,0,0,1,0><<<dim3(C_/128, Mrows/128), blk, 0, stream>>>(
      Abuf, Wqt, bq, posq, N1_ - 1, qb, nullptr, Mrows, C_, C_);
  // MFMA attention -> xatT[b,h,d,q] (region B; vT dead)
  attn_mfma_kernel<<<dim3(N1_/64, H_, B_), blk, 0, stream>>>(
      qb, kpT, vpb, temp, xatT);
  // MLP weight transposes (kpT/vp dead in fallback branch)
  transpose_f2b_kernel<<<dim3(64, 16), blk, 0, stream>>>(W1, W1t, C_,   MLP_, MLP_);
  transpose_f2b_kernel<<<dim3(16, 64), blk, 0, stream>>>(W2, W2t, MLP_, C_,   C_);
  // x = l2norm(scramble(attn) + q) -> region A (x1b dead)
  norm1_kernel<<<dim3(Mrows), blk, 0, stream>>>(xatT, qb, xb);
  // MLP1 + fused MLP2/norm2, chunked (CH rows per chunk)
  for (int c = 0; c < Mrows / CH; ++c) {
    const bf16* xc = xb + (size_t)c * CH * C_;
    mfma_gemm_kernel<128,0,1,0,0><<<dim3(MLP_/128, CH/128), blk, 0, stream>>>(
        xc, W1t, b1, nullptr, 0, hb, nullptr, CH, MLP_, C_);
    mlp2norm_kernel<<<dim3(CH/64), blk, 0, stream>>>(
        hb, W2t, b2, xc, outp + (size_t)c * CH * C_);
  }
}